// Round 6
// baseline (116.508 us; speedup 1.0000x reference)
//
#include <hip/hip_runtime.h>
#include <stdint.h>

// LiftSplatShoot, identity camera — fully static geometry.
// Facts (validated rounds 1-5): only depth bins k=0..11 survive (iz==0);
// all kept points land at ix in [81,118], iy in [89,112]; out[c,ix,iy] =
// sum over points (k,ray)->(ix,iy) of depth[k,ray] * feat[c,ray].
// The point->voxel map is computed at COMPILE TIME (constexpr CSR replicating
// numpy float64 op order; an out-of-range voxel would be a constexpr OOB
// write => compile error).
// Round-6: ONE dispatch, role-split blocks.
//   blocks 0..511    : per-channel patch blocks — stage depth+feat in LDS,
//                      compute 1040 active sums, write the 40 patch rows
//                      (values at cols 88..113, zeros elsewhere).
//   blocks 512..2559 : pure zero-streamers over the non-patch rows
//                      (shift/mask addressing only, nontemporal float4).
// Disjoint regions, every output element written exactly once. No memset.

#define NX0 200
#define NX1 200
#define NC 512
#define FH 24
#define FW 40
#define NRAY (FH * FW)
#define ND 12          // depth bins with iz==0 (d = 4.0 .. 9.5)
#define BX0 80         // patch rows: ix in [80,120)
#define BNX 40
#define BY0 88         // active cols: iy in [88,114)
#define BNY 26
#define NVB (BNX * BNY)
#define NPTS (NRAY * ND)   // 11520 kept points, all in bbox
#define PLANE (NX0 * NX1)  // 40000

typedef float f32x4 __attribute__((ext_vector_type(4)));

struct Tab {
    int      csr[NVB + 1];
    uint32_t ent[NPTS];    // low16 = k*960+ray (flat depth idx), high16 = ray
};

constexpr Tab build_tab() {
    Tab t{};
    int vox[NPTS] = {};
    for (int ray = 0; ray < NRAY; ++ray) {
        const int w = ray % FW, h = ray / FW;
        const double a = 1.0 / 320.0;
        // numpy linspace: y[i] = fl(i * fl(span/(n-1))), endpoint exact
        const double u = (w == FW - 1) ? 639.0 : (double)w * (639.0 / 39.0);
        const double v = (h == FH - 1) ? 383.0 : (double)h * (383.0 / 23.0);
        for (int k = 0; k < ND; ++k) {
            const double d = 4.0 + 0.5 * (double)k;       // arange(4,44,.5)
            const double x = (u * d) * a - d;             // pts @ inv(K).T
            const double y = (v * d) * a - 0.5625 * d;
            const int ix = (int)((x + 50.0) * 2.0);       // trunc toward zero
            const int iy = (int)((y + 50.0) * 2.0);
            vox[k * NRAY + ray] = (ix - BX0) * BNY + (iy - BY0);
        }
    }
    int cnt[NVB] = {};
    for (int i = 0; i < NPTS; ++i) ++cnt[vox[i]];         // OOB => compile err
    t.csr[0] = 0;
    for (int lv = 0; lv < NVB; ++lv) t.csr[lv + 1] = t.csr[lv] + cnt[lv];
    int pos[NVB] = {};
    for (int lv = 0; lv < NVB; ++lv) pos[lv] = t.csr[lv];
    for (int i = 0; i < NPTS; ++i) {
        const int lv  = vox[i];
        const int ray = i % NRAY;                          // i = k*NRAY + ray
        t.ent[pos[lv]++] = (uint32_t)i | ((uint32_t)ray << 16);
    }
    return t;
}

__constant__ Tab c_tab = build_tab();

__global__ __launch_bounds__(256)
void lss_one(const float* __restrict__ feat, const float* __restrict__ depth,
             float* __restrict__ out) {
    const int b   = blockIdx.x;
    const int tid = threadIdx.x;

    if (b < NC) {
        // ---------- patch block: channel c = b ----------
        __shared__ float s_dep[NPTS];    // 46.1 KB (first 12 depth planes)
        __shared__ float s_feat[NRAY];   //  3.8 KB
        __shared__ float s_act[NVB];     //  4.2 KB

        const int c = b;
        const float4* d4 = (const float4*)depth;          // k-major head
        for (int i = tid; i < NPTS / 4; i += 256)
            ((float4*)s_dep)[i] = d4[i];
        if (tid < NRAY / 4)
            ((float4*)s_feat)[tid] = ((const float4*)(feat + c * NRAY))[tid];
        __syncthreads();

        for (int lv = tid; lv < NVB; lv += 256) {
            const int e0 = c_tab.csr[lv], e1 = c_tab.csr[lv + 1];
            float s = 0.0f;
            for (int e = e0; e < e1; ++e) {
                const uint32_t p = c_tab.ent[e];
                s += s_dep[p & 0xFFFFu] * s_feat[p >> 16];
            }
            s_act[lv] = s;
        }
        __syncthreads();

        // write rows 80..119 fully: 40 rows x 50 float4
        float* oc = out + (size_t)c * PLANE + BX0 * NX1;
        for (int idx = tid; idx < BNX * 50; idx += 256) {
            const int row = idx / 50;                      // magic-mul
            const int q   = idx - row * 50;
            f32x4 r = {0.f, 0.f, 0.f, 0.f};
            const float* ar = s_act + row * BNY;
#pragma unroll
            for (int j = 0; j < 4; ++j) {
                const int col = 4 * q + j;
                if ((unsigned)(col - BY0) < BNY) r[j] = ar[col - BY0];
            }
            __builtin_nontemporal_store(r, (f32x4*)(oc + row * NX1 + 4 * q));
        }
    } else {
        // ---------- zero block: quarter-span of non-patch rows ----------
        const int t   = b - NC;          // 0..2047
        const int c   = t >> 2;
        const int q   = t & 3;
        // q0:[0,8000) q1:[8000,16000) q2:[24000,32000) q3:[32000,40000)
        const int off = q * 8000 + ((q >= 2) ? 8000 : 0);
        float* base = out + (size_t)c * PLANE + off;
        const f32x4 z = {0.f, 0.f, 0.f, 0.f};
        for (int i = tid; i < 2000; i += 256)
            __builtin_nontemporal_store(z, (f32x4*)(base + 4 * i));
    }
}

extern "C" void kernel_launch(void* const* d_in, const int* in_sizes, int n_in,
                              void* d_out, int out_size, void* d_ws, size_t ws_size,
                              hipStream_t stream) {
    const float* feat  = (const float*)d_in[0];   // (1, 512, 24, 40)
    const float* depth = (const float*)d_in[1];   // (1, 80, 24, 40)
    float* out = (float*)d_out;                   // (1, 512, 200, 200)

    lss_one<<<NC + 4 * NC, 256, 0, stream>>>(feat, depth, out);
}

// Round 7
// 110.675 us; speedup vs baseline: 1.0527x; 1.0527x over previous
//
#include <hip/hip_runtime.h>
#include <stdint.h>

// LiftSplatShoot, identity camera — fully static geometry.
// Facts (validated rounds 1-6): only depth bins k=0..11 survive (iz==0);
// all kept points land at ix in [81,118], iy in [89,112]; out[c,ix,iy] =
// sum over points (k,ray)->(ix,iy) of depth[k,ray] * feat[c,ray].
// Point->voxel map computed at COMPILE TIME (constexpr CSR replicating numpy
// float64 op order; out-of-range voxel => constexpr OOB => compile error).
// Round-7: single dispatch as round 6, but PLAIN stores (no nontemporal —
// the 6.15 TB/s fillBuffer uses temporal stores) and fully-unrolled zero body.

#define NX0 200
#define NX1 200
#define NC 512
#define FH 24
#define FW 40
#define NRAY (FH * FW)
#define ND 12          // depth bins with iz==0 (d = 4.0 .. 9.5)
#define BX0 80         // patch rows: ix in [80,120)
#define BNX 40
#define BY0 88         // active cols: iy in [88,114)
#define BNY 26
#define NVB (BNX * BNY)
#define NPTS (NRAY * ND)   // 11520 kept points, all in bbox
#define PLANE (NX0 * NX1)  // 40000

typedef float f32x4 __attribute__((ext_vector_type(4)));

struct Tab {
    int      csr[NVB + 1];
    uint32_t ent[NPTS];    // low16 = k*960+ray (flat depth idx), high16 = ray
};

constexpr Tab build_tab() {
    Tab t{};
    int vox[NPTS] = {};
    for (int ray = 0; ray < NRAY; ++ray) {
        const int w = ray % FW, h = ray / FW;
        const double a = 1.0 / 320.0;
        // numpy linspace: y[i] = fl(i * fl(span/(n-1))), endpoint exact
        const double u = (w == FW - 1) ? 639.0 : (double)w * (639.0 / 39.0);
        const double v = (h == FH - 1) ? 383.0 : (double)h * (383.0 / 23.0);
        for (int k = 0; k < ND; ++k) {
            const double d = 4.0 + 0.5 * (double)k;       // arange(4,44,.5)
            const double x = (u * d) * a - d;             // pts @ inv(K).T
            const double y = (v * d) * a - 0.5625 * d;
            const int ix = (int)((x + 50.0) * 2.0);       // trunc toward zero
            const int iy = (int)((y + 50.0) * 2.0);
            vox[k * NRAY + ray] = (ix - BX0) * BNY + (iy - BY0);
        }
    }
    int cnt[NVB] = {};
    for (int i = 0; i < NPTS; ++i) ++cnt[vox[i]];         // OOB => compile err
    t.csr[0] = 0;
    for (int lv = 0; lv < NVB; ++lv) t.csr[lv + 1] = t.csr[lv] + cnt[lv];
    int pos[NVB] = {};
    for (int lv = 0; lv < NVB; ++lv) pos[lv] = t.csr[lv];
    for (int i = 0; i < NPTS; ++i) {
        const int lv  = vox[i];
        const int ray = i % NRAY;                          // i = k*NRAY + ray
        t.ent[pos[lv]++] = (uint32_t)i | ((uint32_t)ray << 16);
    }
    return t;
}

__constant__ Tab c_tab = build_tab();

__global__ __launch_bounds__(256)
void lss_one(const float* __restrict__ feat, const float* __restrict__ depth,
             float* __restrict__ out) {
    const int b   = blockIdx.x;
    const int tid = threadIdx.x;

    if (b < NC) {
        // ---------- patch block: channel c = b ----------
        __shared__ float s_dep[NPTS];    // 46.1 KB (first 12 depth planes)
        __shared__ float s_feat[NRAY];   //  3.8 KB
        __shared__ float s_act[NVB];     //  4.2 KB

        const int c = b;
        const float4* d4 = (const float4*)depth;          // k-major head
        for (int i = tid; i < NPTS / 4; i += 256)
            ((float4*)s_dep)[i] = d4[i];
        if (tid < NRAY / 4)
            ((float4*)s_feat)[tid] = ((const float4*)(feat + c * NRAY))[tid];
        __syncthreads();

        for (int lv = tid; lv < NVB; lv += 256) {
            const int e0 = c_tab.csr[lv], e1 = c_tab.csr[lv + 1];
            float s = 0.0f;
            for (int e = e0; e < e1; ++e) {
                const uint32_t p = c_tab.ent[e];
                s += s_dep[p & 0xFFFFu] * s_feat[p >> 16];
            }
            s_act[lv] = s;
        }
        __syncthreads();

        // write rows 80..119 fully: 40 rows x 50 float4 (plain stores)
        float* oc = out + (size_t)c * PLANE + BX0 * NX1;
        for (int idx = tid; idx < BNX * 50; idx += 256) {
            const int row = idx / 50;                      // magic-mul
            const int q   = idx - row * 50;
            f32x4 r = {0.f, 0.f, 0.f, 0.f};
            const float* ar = s_act + row * BNY;
#pragma unroll
            for (int j = 0; j < 4; ++j) {
                const int col = 4 * q + j;
                if ((unsigned)(col - BY0) < BNY) r[j] = ar[col - BY0];
            }
            *(f32x4*)(oc + row * NX1 + 4 * q) = r;
        }
    } else {
        // ---------- zero block: quarter-span of non-patch rows ----------
        const int t   = b - NC;          // 0..2047
        const int c   = t >> 2;
        const int q   = t & 3;
        // q0:[0,8000) q1:[8000,16000) q2:[24000,32000) q3:[32000,40000)
        const int off = q * 8000 + ((q >= 2) ? 8000 : 0);
        f32x4* base = (f32x4*)(out + (size_t)c * PLANE + off);
        const f32x4 z = {0.f, 0.f, 0.f, 0.f};
#pragma unroll
        for (int i = 0; i < 8; ++i)                        // 8 x 256 = 2000+
            if (i * 256 + tid < 2000)
                base[i * 256 + tid] = z;
    }
}

extern "C" void kernel_launch(void* const* d_in, const int* in_sizes, int n_in,
                              void* d_out, int out_size, void* d_ws, size_t ws_size,
                              hipStream_t stream) {
    const float* feat  = (const float*)d_in[0];   // (1, 512, 24, 40)
    const float* depth = (const float*)d_in[1];   // (1, 80, 24, 40)
    float* out = (float*)d_out;                   // (1, 512, 200, 200)

    lss_one<<<NC + 4 * NC, 256, 0, stream>>>(feat, depth, out);
}